// Round 8
// baseline (805.380 us; speedup 1.0000x reference)
//
#include <hip/hip_runtime.h>
#include <hip/hip_bf16.h>
#include <hip/hip_fp16.h>

#define H_DIM 128
#define BN_EPS 1e-5f

typedef _Float16 half8 __attribute__((ext_vector_type(8)));
typedef float floatx4 __attribute__((ext_vector_type(4)));

// Intermediate activations are stored GROUP-MAJOR: G[g][n][16] fp16, g=0..7.
// Channel c lives at slice g=c>>4, offset c&15. Written by GEMM epilogue
// (nt tile == group), gathered by aggregate with blockIdx%8==g so each XCD's
// random gathers stay inside one 3.2MB slice (L2-resident).

// ---------------- degree ----------------
__global__ void degree_kernel(const int* __restrict__ dst, int* __restrict__ deg, int E_) {
    int i = blockIdx.x * blockDim.x + threadIdx.x;
    if (i < E_) atomicAdd(&deg[dst[i]], 1);
}

// ---------------- exclusive scan (3-kernel), dinv fused into pass 1 ----------------
__global__ void scan_block_kernel(const int* __restrict__ deg, float* __restrict__ dinv,
                                  int* __restrict__ rowptr, int* __restrict__ bsum, int N_) {
    __shared__ int sh[256];
    int i = blockIdx.x * 256 + threadIdx.x;
    int v = (i < N_) ? deg[i] : 0;
    if (i < N_) dinv[i] = rsqrtf((float)v + 1.0f);
    sh[threadIdx.x] = v;
    __syncthreads();
    for (int off = 1; off < 256; off <<= 1) {
        int t = (threadIdx.x >= off) ? sh[threadIdx.x - off] : 0;
        __syncthreads();
        sh[threadIdx.x] += t;
        __syncthreads();
    }
    if (i < N_) rowptr[i] = sh[threadIdx.x] - v;   // exclusive
    if (threadIdx.x == 255) bsum[blockIdx.x] = sh[255];
}

__global__ void scan_bsums_kernel(const int* __restrict__ bsum, int* __restrict__ boff, int nb) {
    __shared__ int sh[512];
    int v = (threadIdx.x < nb) ? bsum[threadIdx.x] : 0;
    sh[threadIdx.x] = v;
    __syncthreads();
    for (int off = 1; off < 512; off <<= 1) {
        int t = (threadIdx.x >= off) ? sh[threadIdx.x - off] : 0;
        __syncthreads();
        sh[threadIdx.x] += t;
        __syncthreads();
    }
    if (threadIdx.x < nb) boff[threadIdx.x] = sh[threadIdx.x] - v;  // exclusive
}

__global__ void scan_add_kernel(int* __restrict__ rowptr, const int* __restrict__ boff,
                                int N_, int E_) {
    int i = blockIdx.x * 256 + threadIdx.x;
    if (i < N_) rowptr[i] += boff[blockIdx.x];
    if (i == 0) rowptr[N_] = E_;
}

// ---------------- CSR fill, XCD-binned by dst bucket ----------------
__global__ void csr_fill_kernel(const int* __restrict__ src, const int* __restrict__ dst,
                                const int* __restrict__ rowptr, int* __restrict__ cursor,
                                int* __restrict__ cols, int E_, int N_, int shift) {
    int b = blockIdx.x & 7;
    if (((N_ - 1) >> shift) < b) return;          // bucket never occurs
    int i = (blockIdx.x >> 3) * blockDim.x + threadIdx.x;
    if (i < E_) {
        int d = dst[i];
        if ((d >> shift) == b) {
            int p = rowptr[d] + atomicAdd(&cursor[d], 1);
            cols[p] = src[i];
        }
    }
}

// ---------------- MFMA fragment helpers ----------------
__device__ inline half8 a_frag_f32(const float* Xr, int k0) {
    float4 v0 = *(const float4*)(Xr + k0);
    float4 v1 = *(const float4*)(Xr + k0 + 4);
    half8 a;
    a[0] = (_Float16)v0.x; a[1] = (_Float16)v0.y; a[2] = (_Float16)v0.z; a[3] = (_Float16)v0.w;
    a[4] = (_Float16)v1.x; a[5] = (_Float16)v1.y; a[6] = (_Float16)v1.z; a[7] = (_Float16)v1.w;
    return a;
}
// group-major A-fragment with fused BN+ReLU; p8 -> 8 contiguous halfs of channel k0..k0+7
__device__ inline half8 a_frag_f16_bn(const _Float16* p8, int k0,
                                      const float* A, const float* B) {
    half8 r = *(const half8*)p8;
    half8 o;
#pragma unroll
    for (int u = 0; u < 8; ++u)
        o[u] = (_Float16)fmaxf(fmaf((float)r[u], A[k0 + u], B[k0 + u]), 0.f);
    return o;
}
__device__ inline const _Float16* gm_ptr(const _Float16* X, int N_, int row, int k0) {
    return X + ((size_t)(k0 >> 4) * N_ + row) * 16 + (k0 & 15);
}

// ---------------- MFMA GEMM: G'[g][n][16] = dinv .* (bnrelu(X) @ W[128,128]) ----------------
template<bool BN, typename InT>
__global__ __launch_bounds__(256) void gemm_mfma_kernel(
    const InT* __restrict__ X, const float* __restrict__ W,
    const float* __restrict__ gsum, const float* __restrict__ gsq,
    const float* __restrict__ gamma, const float* __restrict__ beta,
    const float* __restrict__ dinv,
    _Float16* __restrict__ Y, int N_, float inv_n)
{
    __shared__ _Float16 Wf[32 * 64 * 8];   // 32 KB: [nt*4+kb][lane][j]
    __shared__ float Abn[128], Bbn[128];

    const int tid = threadIdx.x;
    for (int idx = tid; idx < 128 * 32; idx += 256) {
        int k = idx >> 5;                   // 0..127
        int n0 = (idx & 31) * 4;
        float4 w = *(const float4*)(W + k * 128 + n0);
        int kb = k >> 5, q = (k >> 3) & 3, j = k & 7;
#pragma unroll
        for (int u = 0; u < 4; ++u) {
            int n = n0 + u;
            int lane = (n & 15) | (q << 4);
            Wf[((((n >> 4) * 4 + kb) * 64 + lane) << 3) + j] = (_Float16)((&w.x)[u]);
        }
    }
    if constexpr (BN) {
        if (tid < 128) {
            float mean = gsum[tid] * inv_n;
            float var = gsq[tid] * inv_n - mean * mean;
            float a = rsqrtf(var + BN_EPS) * gamma[tid];
            Abn[tid] = a;
            Bbn[tid] = beta[tid] - mean * a;
        }
    }
    __syncthreads();

    const int wv = tid >> 6, lane = tid & 63;
    const int m = lane & 15, q = lane >> 4;
    const int row0 = blockIdx.x * 64 + wv * 16;

    int arow = row0 + m;
    if (arow >= N_) arow = N_ - 1;

    half8 a[4];
#pragma unroll
    for (int kb = 0; kb < 4; ++kb) {
        int k0 = kb * 32 + q * 8;
        if constexpr (BN)
            a[kb] = a_frag_f16_bn(gm_ptr((const _Float16*)X, N_, arow, k0), k0, Abn, Bbn);
        else
            a[kb] = a_frag_f32((const float*)X + (size_t)arow * H_DIM, k0);
    }

    floatx4 acc[8];
#pragma unroll
    for (int nt = 0; nt < 8; ++nt) acc[nt] = (floatx4){0.f, 0.f, 0.f, 0.f};

#pragma unroll
    for (int nt = 0; nt < 8; ++nt) {
#pragma unroll
        for (int kb = 0; kb < 4; ++kb) {
            half8 b = *(const half8*)&Wf[(((nt * 4 + kb) * 64 + lane) << 3)];
            acc[nt] = __builtin_amdgcn_mfma_f32_16x16x32_f16(a[kb], b, acc[nt], 0, 0, 0);
        }
    }

#pragma unroll
    for (int r = 0; r < 4; ++r) {
        int row = row0 + q * 4 + r;
        if (row < N_) {
            float ds = dinv[row];
#pragma unroll
            for (int nt = 0; nt < 8; ++nt)
                Y[((size_t)nt * N_ + row) * 16 + m] = (_Float16)(ds * acc[nt][r]);
        }
    }
}

// ---------------- MFMA readout: Y[N,40] = bnrelu(X_gm) @ Wr[128,40] + br ----------------
__global__ __launch_bounds__(256) void readout_mfma_kernel(
    const _Float16* __restrict__ X, const float* __restrict__ W,   // [128, OUTC]
    const float* __restrict__ gsum, const float* __restrict__ gsq,
    const float* __restrict__ gamma, const float* __restrict__ beta,
    const float* __restrict__ br,
    float* __restrict__ Y, int N_, int OUTC, float inv_n)
{
    __shared__ _Float16 Wf[12 * 64 * 8];   // 12 KB: 3 n-tiles (48 cols padded)
    __shared__ float Abn[128], Bbn[128];

    const int tid = threadIdx.x;
    for (int idx = tid; idx < 128 * 64; idx += 256) {
        int k = idx >> 6, n = idx & 63;
        if (n < 48) {
            float w = (n < OUTC) ? W[k * OUTC + n] : 0.f;
            int kb = k >> 5, q = (k >> 3) & 3, j = k & 7;
            int lane = (n & 15) | (q << 4);
            Wf[((((n >> 4) * 4 + kb) * 64 + lane) << 3) + j] = (_Float16)w;
        }
    }
    if (tid < 128) {
        float mean = gsum[tid] * inv_n;
        float var = gsq[tid] * inv_n - mean * mean;
        float a = rsqrtf(var + BN_EPS) * gamma[tid];
        Abn[tid] = a;
        Bbn[tid] = beta[tid] - mean * a;
    }
    __syncthreads();

    const int wv = tid >> 6, lane = tid & 63;
    const int m = lane & 15, q = lane >> 4;
    const int row0 = blockIdx.x * 64 + wv * 16;

    int arow = row0 + m;
    if (arow >= N_) arow = N_ - 1;

    half8 a[4];
#pragma unroll
    for (int kb = 0; kb < 4; ++kb) {
        int k0 = kb * 32 + q * 8;
        a[kb] = a_frag_f16_bn(gm_ptr(X, N_, arow, k0), k0, Abn, Bbn);
    }

    floatx4 acc[3];
#pragma unroll
    for (int nt = 0; nt < 3; ++nt) acc[nt] = (floatx4){0.f, 0.f, 0.f, 0.f};

#pragma unroll
    for (int nt = 0; nt < 3; ++nt) {
#pragma unroll
        for (int kb = 0; kb < 4; ++kb) {
            half8 b = *(const half8*)&Wf[(((nt * 4 + kb) * 64 + lane) << 3)];
            acc[nt] = __builtin_amdgcn_mfma_f32_16x16x32_f16(a[kb], b, acc[nt], 0, 0, 0);
        }
    }

#pragma unroll
    for (int nt = 0; nt < 3; ++nt) {
        int col = nt * 16 + m;
        if (col < OUTC) {
            float bb = br[col];
#pragma unroll
            for (int r = 0; r < 4; ++r) {
                int row = row0 + q * 4 + r;
                if (row < N_)
                    Y[(size_t)row * OUTC + col] = acc[nt][r] + bb;
            }
        }
    }
}

// ---------------- aggregation, channel-split: out[g][d] = dinv[d]*(G[g][d]+sum G[g][src]) + b ----
// blockIdx%8 = channel group (XCD-local 3.2MB slice). Wave = one node:
// lane = 8*eo + cp; 8 edges gathered per VMEM instr (32B each); fp16 pk accum;
// shfl_xor tree over edge slots; lanes eo==0 store 16 channels.
__global__ __launch_bounds__(256) void aggregate_kernel(
    const __half2* __restrict__ Gp,           // [8][N][8] half2
    const int* __restrict__ rowptr,
    const int* __restrict__ cols,
    const float* __restrict__ dinv, const float* __restrict__ bias,
    __half2* __restrict__ out, int N_)
{
    const int g = blockIdx.x & 7;
    const int wave = threadIdx.x >> 6;
    const int lane = threadIdx.x & 63;
    const int eo = lane >> 3;                 // edge slot 0..7
    const int cp = lane & 7;                  // half2 index 0..7 (16 channels)
    const int n = (blockIdx.x >> 3) * 4 + wave;
    if (n >= N_) return;

    const __half2* Gs = Gp + (size_t)g * N_ * 8;
    const __half2 z = __float2half2_rn(0.f);
    __half2 a0 = z, a1 = z;

    const int r0 = rowptr[n], r1 = rowptr[n + 1];
    int e = r0 + eo;
    for (; e + 8 < r1; e += 16) {
        int s0 = cols[e], s1 = cols[e + 8];
        __half2 h0 = Gs[(size_t)s0 * 8 + cp];
        __half2 h1 = Gs[(size_t)s1 * 8 + cp];
        a0 = __hadd2(a0, h0);
        a1 = __hadd2(a1, h1);
    }
    if (e < r1) a0 = __hadd2(a0, Gs[(size_t)cols[e] * 8 + cp]);
    __half2 acc = __hadd2(a0, a1);

#pragma unroll
    for (int mask = 8; mask < 64; mask <<= 1) {
        int v = __shfl_xor(*(int*)&acc, mask);
        acc = __hadd2(acc, *(__half2*)&v);
    }

    if (eo == 0) {
        __half2 self = Gs[(size_t)n * 8 + cp];
        float2 s = __half22float2(__hadd2(acc, self));
        float di = dinv[n];
        float2 bb = ((const float2*)bias)[g * 8 + cp];
        float o0 = fmaf(di, s.x, bb.x);
        float o1 = fmaf(di, s.y, bb.y);
        out[((size_t)g * N_ + n) * 8 + cp] = __floats2half2_rn(o0, o1);
    }
}

// ---------------- BN stats over group-major input ----------------
__global__ __launch_bounds__(256) void bn_stats_kernel(
    const __half2* __restrict__ X, float* __restrict__ gsum, float* __restrict__ gsq,
    int N_, int stride)
{
    __shared__ float ssum[4][128], ssq[4][128];
    const int wave = threadIdx.x >> 6;
    const int lane = threadIdx.x & 63;
    const size_t base = (size_t)(lane >> 3) * N_ * 8 + (lane & 7);
    float r0 = 0.f, r1 = 0.f, q0 = 0.f, q1 = 0.f;
    for (int n = blockIdx.x * 4 + wave; n < N_; n += stride) {
        float2 v = __half22float2(X[base + (size_t)n * 8]);
        r0 += v.x; r1 += v.y;
        q0 = fmaf(v.x, v.x, q0); q1 = fmaf(v.y, v.y, q1);
    }
    int c = lane * 2;   // channel = (lane>>3)*16 + (lane&7)*2 == 2*lane
    ssum[wave][c] = r0; ssum[wave][c + 1] = r1;
    ssq[wave][c]  = q0; ssq[wave][c + 1]  = q1;
    __syncthreads();
    if (threadIdx.x < 128) {
        int k = threadIdx.x;
        float s = (ssum[0][k] + ssum[1][k]) + (ssum[2][k] + ssum[3][k]);
        float q = (ssq[0][k] + ssq[1][k]) + (ssq[2][k] + ssq[3][k]);
        atomicAdd(&gsum[k], s);
        atomicAdd(&gsq[k], q);
    }
}

// ---------------- launch ----------------
extern "C" void kernel_launch(void* const* d_in, const int* in_sizes, int n_in,
                              void* d_out, int out_size, void* d_ws, size_t ws_size,
                              hipStream_t stream) {
    const float* x   = (const float*)d_in[0];
    const int* esrc  = (const int*)d_in[1];
    const int* edst  = (const int*)d_in[2];
    const float* W1  = (const float*)d_in[3];
    const float* b1  = (const float*)d_in[4];
    const float* g1  = (const float*)d_in[5];
    const float* bt1 = (const float*)d_in[6];
    const float* W2  = (const float*)d_in[7];
    const float* b2  = (const float*)d_in[8];
    const float* g2  = (const float*)d_in[9];
    const float* bt2 = (const float*)d_in[10];
    const float* Wr  = (const float*)d_in[11];
    const float* br  = (const float*)d_in[12];

    const int N_ = in_sizes[0] / H_DIM;     // 100000
    const int E_ = in_sizes[1];             // 1600000
    const int OUTC = out_size / N_;         // 40
    const float inv_n = 1.0f / (float)N_;

    char* p = (char*)d_ws;
    auto alloc = [&](size_t bytes) -> void* {
        void* r = (void*)p;
        p += (bytes + 255) & ~(size_t)255;
        return r;
    };
    __half* tmpA = (__half*)alloc((size_t)N_ * H_DIM * 2);
    __half* tmpB = (__half*)alloc((size_t)N_ * H_DIM * 2);
    int*   cols  = (int*)  alloc((size_t)E_ * 4);
    int*   rowptr= (int*)  alloc((size_t)(N_ + 1) * 4);
    size_t degcur_sz = ((size_t)2 * N_ * 4 + 255) & ~(size_t)255;
    int*   degcur= (int*)  alloc((size_t)2 * N_ * 4);
    float* bnbuf = (float*)alloc(4 * 128 * 4);
    int*   deg   = degcur;
    int*   cursor= degcur + N_;
    float* sum1 = bnbuf,       *sq1 = bnbuf + 128;
    float* sum2 = bnbuf + 256, *sq2 = bnbuf + 384;
    float* dinv  = (float*)alloc((size_t)N_ * 4);
    int*   bsum  = (int*)  alloc(4096);
    int*   boff  = (int*)  alloc(4096);

    hipMemsetAsync(degcur, 0, degcur_sz + 4 * 128 * 4, stream);  // deg+cursor+bn sums

    const int nb = (N_ + 255) / 256;
    const int eb = (E_ + 255) / 256;
    const int ntiles64 = (N_ + 63) / 64;
    const int agg_grid = ((N_ + 3) / 4) * 8;

    int shift = 0;                           // buckets (d>>shift) in 0..7
    while (((N_ - 1) >> shift) > 7) ++shift; // N=100000 -> shift=14, buckets 0..6

    const int BN_BLOCKS = 1024;
    const int BN_STRIDE = BN_BLOCKS * 4;

    degree_kernel<<<eb, 256, 0, stream>>>(edst, deg, E_);
    scan_block_kernel<<<nb, 256, 0, stream>>>(deg, dinv, rowptr, bsum, N_);
    scan_bsums_kernel<<<1, 512, 0, stream>>>(bsum, boff, nb);
    scan_add_kernel<<<nb, 256, 0, stream>>>(rowptr, boff, N_, E_);
    csr_fill_kernel<<<eb * 8, 256, 0, stream>>>(esrc, edst, rowptr, cursor, cols, E_, N_, shift);

    // layer 1: G1 = dinv .* (x @ W1)   (f32 row-major in, fp16 group-major out)
    gemm_mfma_kernel<false, float><<<ntiles64, 256, 0, stream>>>(
        x, W1, nullptr, nullptr, nullptr, nullptr, dinv,
        (_Float16*)tmpA, N_, inv_n);
    aggregate_kernel<<<agg_grid, 256, 0, stream>>>(
        (const __half2*)tmpA, rowptr, cols, dinv, b1, (__half2*)tmpB, N_);
    bn_stats_kernel<<<BN_BLOCKS, 256, 0, stream>>>(
        (const __half2*)tmpB, sum1, sq1, N_, BN_STRIDE);

    // layer 2 (BN-finalize fused into GEMM prologue; group-major in/out)
    gemm_mfma_kernel<true, _Float16><<<ntiles64, 256, 0, stream>>>(
        (const _Float16*)tmpB, W2, sum1, sq1, g1, bt1, dinv,
        (_Float16*)tmpA, N_, inv_n);
    aggregate_kernel<<<agg_grid, 256, 0, stream>>>(
        (const __half2*)tmpA, rowptr, cols, dinv, b2, (__half2*)tmpB, N_);
    bn_stats_kernel<<<BN_BLOCKS, 256, 0, stream>>>(
        (const __half2*)tmpB, sum2, sq2, N_, BN_STRIDE);

    // readout (MFMA, BN-finalize + bias fused, f32 row-major out)
    readout_mfma_kernel<<<ntiles64, 256, 0, stream>>>(
        (const _Float16*)tmpB, Wr, sum2, sq2, g2, bt2, br,
        (float*)d_out, N_, OUTC, inv_n);
}

// Round 9
// 627.911 us; speedup vs baseline: 1.2826x; 1.2826x over previous
//
#include <hip/hip_runtime.h>
#include <hip/hip_bf16.h>
#include <hip/hip_fp16.h>

#define H_DIM 128
#define BN_EPS 1e-5f

typedef _Float16 half8 __attribute__((ext_vector_type(8)));
typedef float floatx4 __attribute__((ext_vector_type(4)));

// Intermediate activations are stored GROUP-MAJOR: G[g][n][16] fp16, g=0..7.
// Channel c lives at slice g=c>>4, offset c&15. Written by GEMM epilogue
// (nt tile == group), gathered by aggregate with blockIdx%8==g so each XCD's
// random gathers stay inside one 3.2MB slice (L2-resident). [R8: FETCH 190->43MB]

// ---------------- degree ----------------
__global__ void degree_kernel(const int* __restrict__ dst, int* __restrict__ deg, int E_) {
    int i = blockIdx.x * blockDim.x + threadIdx.x;
    if (i < E_) atomicAdd(&deg[dst[i]], 1);
}

// ---------------- exclusive scan (3-kernel), dinv fused into pass 1 ----------------
__global__ void scan_block_kernel(const int* __restrict__ deg, float* __restrict__ dinv,
                                  int* __restrict__ rowptr, int* __restrict__ bsum, int N_) {
    __shared__ int sh[256];
    int i = blockIdx.x * 256 + threadIdx.x;
    int v = (i < N_) ? deg[i] : 0;
    if (i < N_) dinv[i] = rsqrtf((float)v + 1.0f);
    sh[threadIdx.x] = v;
    __syncthreads();
    for (int off = 1; off < 256; off <<= 1) {
        int t = (threadIdx.x >= off) ? sh[threadIdx.x - off] : 0;
        __syncthreads();
        sh[threadIdx.x] += t;
        __syncthreads();
    }
    if (i < N_) rowptr[i] = sh[threadIdx.x] - v;   // exclusive
    if (threadIdx.x == 255) bsum[blockIdx.x] = sh[255];
}

__global__ void scan_bsums_kernel(const int* __restrict__ bsum, int* __restrict__ boff, int nb) {
    __shared__ int sh[512];
    int v = (threadIdx.x < nb) ? bsum[threadIdx.x] : 0;
    sh[threadIdx.x] = v;
    __syncthreads();
    for (int off = 1; off < 512; off <<= 1) {
        int t = (threadIdx.x >= off) ? sh[threadIdx.x - off] : 0;
        __syncthreads();
        sh[threadIdx.x] += t;
        __syncthreads();
    }
    if (threadIdx.x < nb) boff[threadIdx.x] = sh[threadIdx.x] - v;  // exclusive
}

__global__ void scan_add_kernel(int* __restrict__ rowptr, const int* __restrict__ boff,
                                int N_, int E_) {
    int i = blockIdx.x * 256 + threadIdx.x;
    if (i < N_) rowptr[i] += boff[blockIdx.x];
    if (i == 0) rowptr[N_] = E_;
}

// ---------------- CSR fill, XCD-binned by dst bucket ----------------
__global__ void csr_fill_kernel(const int* __restrict__ src, const int* __restrict__ dst,
                                const int* __restrict__ rowptr, int* __restrict__ cursor,
                                int* __restrict__ cols, int E_, int N_, int shift) {
    int b = blockIdx.x & 7;
    if (((N_ - 1) >> shift) < b) return;          // bucket never occurs
    int i = (blockIdx.x >> 3) * blockDim.x + threadIdx.x;
    if (i < E_) {
        int d = dst[i];
        if ((d >> shift) == b) {
            int p = rowptr[d] + atomicAdd(&cursor[d], 1);
            cols[p] = src[i];
        }
    }
}

// ---------------- MFMA fragment helpers ----------------
__device__ inline half8 a_frag_f32(const float* Xr, int k0) {
    float4 v0 = *(const float4*)(Xr + k0);
    float4 v1 = *(const float4*)(Xr + k0 + 4);
    half8 a;
    a[0] = (_Float16)v0.x; a[1] = (_Float16)v0.y; a[2] = (_Float16)v0.z; a[3] = (_Float16)v0.w;
    a[4] = (_Float16)v1.x; a[5] = (_Float16)v1.y; a[6] = (_Float16)v1.z; a[7] = (_Float16)v1.w;
    return a;
}
// group-major A-fragment with fused BN+ReLU; p8 -> 8 contiguous halfs of channel k0..k0+7
__device__ inline half8 a_frag_f16_bn(const _Float16* p8, int k0,
                                      const float* A, const float* B) {
    half8 r = *(const half8*)p8;
    half8 o;
#pragma unroll
    for (int u = 0; u < 8; ++u)
        o[u] = (_Float16)fmaxf(fmaf((float)r[u], A[k0 + u], B[k0 + u]), 0.f);
    return o;
}
__device__ inline const _Float16* gm_ptr(const _Float16* X, int N_, int row, int k0) {
    return X + ((size_t)(k0 >> 4) * N_ + row) * 16 + (k0 & 15);
}

// ---------------- MFMA GEMM: G'[g][n][16] = dinv .* (bnrelu(X) @ W[128,128]) ----------------
template<bool BN, typename InT>
__global__ __launch_bounds__(256) void gemm_mfma_kernel(
    const InT* __restrict__ X, const float* __restrict__ W,
    const float* __restrict__ gsum, const float* __restrict__ gsq,
    const float* __restrict__ gamma, const float* __restrict__ beta,
    const float* __restrict__ dinv,
    _Float16* __restrict__ Y, int N_, float inv_n)
{
    __shared__ _Float16 Wf[32 * 64 * 8];   // 32 KB: [nt*4+kb][lane][j]
    __shared__ float Abn[128], Bbn[128];

    const int tid = threadIdx.x;
    for (int idx = tid; idx < 128 * 32; idx += 256) {
        int k = idx >> 5;                   // 0..127
        int n0 = (idx & 31) * 4;
        float4 w = *(const float4*)(W + k * 128 + n0);
        int kb = k >> 5, q = (k >> 3) & 3, j = k & 7;
#pragma unroll
        for (int u = 0; u < 4; ++u) {
            int n = n0 + u;
            int lane = (n & 15) | (q << 4);
            Wf[((((n >> 4) * 4 + kb) * 64 + lane) << 3) + j] = (_Float16)((&w.x)[u]);
        }
    }
    if constexpr (BN) {
        if (tid < 128) {
            float mean = gsum[tid] * inv_n;
            float var = gsq[tid] * inv_n - mean * mean;
            float a = rsqrtf(var + BN_EPS) * gamma[tid];
            Abn[tid] = a;
            Bbn[tid] = beta[tid] - mean * a;
        }
    }
    __syncthreads();

    const int wv = tid >> 6, lane = tid & 63;
    const int m = lane & 15, q = lane >> 4;
    const int row0 = blockIdx.x * 64 + wv * 16;

    int arow = row0 + m;
    if (arow >= N_) arow = N_ - 1;

    half8 a[4];
#pragma unroll
    for (int kb = 0; kb < 4; ++kb) {
        int k0 = kb * 32 + q * 8;
        if constexpr (BN)
            a[kb] = a_frag_f16_bn(gm_ptr((const _Float16*)X, N_, arow, k0), k0, Abn, Bbn);
        else
            a[kb] = a_frag_f32((const float*)X + (size_t)arow * H_DIM, k0);
    }

    floatx4 acc[8];
#pragma unroll
    for (int nt = 0; nt < 8; ++nt) acc[nt] = (floatx4){0.f, 0.f, 0.f, 0.f};

#pragma unroll
    for (int nt = 0; nt < 8; ++nt) {
#pragma unroll
        for (int kb = 0; kb < 4; ++kb) {
            half8 b = *(const half8*)&Wf[(((nt * 4 + kb) * 64 + lane) << 3)];
            acc[nt] = __builtin_amdgcn_mfma_f32_16x16x32_f16(a[kb], b, acc[nt], 0, 0, 0);
        }
    }

#pragma unroll
    for (int r = 0; r < 4; ++r) {
        int row = row0 + q * 4 + r;
        if (row < N_) {
            float ds = dinv[row];
#pragma unroll
            for (int nt = 0; nt < 8; ++nt)
                Y[((size_t)nt * N_ + row) * 16 + m] = (_Float16)(ds * acc[nt][r]);
        }
    }
}

// ---------------- MFMA readout: Y[N,40] = bnrelu(X_gm) @ Wr[128,40] + br ----------------
__global__ __launch_bounds__(256) void readout_mfma_kernel(
    const _Float16* __restrict__ X, const float* __restrict__ W,   // [128, OUTC]
    const float* __restrict__ gsum, const float* __restrict__ gsq,
    const float* __restrict__ gamma, const float* __restrict__ beta,
    const float* __restrict__ br,
    float* __restrict__ Y, int N_, int OUTC, float inv_n)
{
    __shared__ _Float16 Wf[12 * 64 * 8];   // 12 KB: 3 n-tiles (48 cols padded)
    __shared__ float Abn[128], Bbn[128];

    const int tid = threadIdx.x;
    for (int idx = tid; idx < 128 * 64; idx += 256) {
        int k = idx >> 6, n = idx & 63;
        if (n < 48) {
            float w = (n < OUTC) ? W[k * OUTC + n] : 0.f;
            int kb = k >> 5, q = (k >> 3) & 3, j = k & 7;
            int lane = (n & 15) | (q << 4);
            Wf[((((n >> 4) * 4 + kb) * 64 + lane) << 3) + j] = (_Float16)w;
        }
    }
    if (tid < 128) {
        float mean = gsum[tid] * inv_n;
        float var = gsq[tid] * inv_n - mean * mean;
        float a = rsqrtf(var + BN_EPS) * gamma[tid];
        Abn[tid] = a;
        Bbn[tid] = beta[tid] - mean * a;
    }
    __syncthreads();

    const int wv = tid >> 6, lane = tid & 63;
    const int m = lane & 15, q = lane >> 4;
    const int row0 = blockIdx.x * 64 + wv * 16;

    int arow = row0 + m;
    if (arow >= N_) arow = N_ - 1;

    half8 a[4];
#pragma unroll
    for (int kb = 0; kb < 4; ++kb) {
        int k0 = kb * 32 + q * 8;
        a[kb] = a_frag_f16_bn(gm_ptr(X, N_, arow, k0), k0, Abn, Bbn);
    }

    floatx4 acc[3];
#pragma unroll
    for (int nt = 0; nt < 3; ++nt) acc[nt] = (floatx4){0.f, 0.f, 0.f, 0.f};

#pragma unroll
    for (int nt = 0; nt < 3; ++nt) {
#pragma unroll
        for (int kb = 0; kb < 4; ++kb) {
            half8 b = *(const half8*)&Wf[(((nt * 4 + kb) * 64 + lane) << 3)];
            acc[nt] = __builtin_amdgcn_mfma_f32_16x16x32_f16(a[kb], b, acc[nt], 0, 0, 0);
        }
    }

#pragma unroll
    for (int nt = 0; nt < 3; ++nt) {
        int col = nt * 16 + m;
        if (col < OUTC) {
            float bb = br[col];
#pragma unroll
            for (int r = 0; r < 4; ++r) {
                int row = row0 + q * 4 + r;
                if (row < N_)
                    Y[(size_t)row * OUTC + col] = acc[nt][r] + bb;
            }
        }
    }
}

// ---------------- aggregation, channel-split v3 ----------------
// blockIdx%8 = group g (XCD-local 3.2MB slice). Wave = 8 consecutive nodes of
// one group: lane = ni*8 + cp. Each 8-lane slice walks its node's edge list
// (2-way unrolled -> 16 gathers in flight/wave), predicated by clamp+select;
// no cross-lane reduction needed; self-load & store are 256B contiguous.
__global__ __launch_bounds__(256) void aggregate_kernel(
    const __half2* __restrict__ Gp,           // [8][N][8] half2
    const int* __restrict__ rowptr,
    const int* __restrict__ cols,
    const float* __restrict__ dinv, const float* __restrict__ bias,
    __half2* __restrict__ out, int N_, int E_)
{
    const int g = blockIdx.x & 7;
    const int wave = threadIdx.x >> 6;
    const int lane = threadIdx.x & 63;
    const int ni = lane >> 3;                 // node slot 0..7
    const int cp = lane & 7;                  // half2 channel index 0..7
    const int n0 = ((blockIdx.x >> 3) * 4 + wave) * 8;
    if (n0 >= N_) return;
    int n = n0 + ni;
    const bool valid = n < N_;
    if (!valid) n = N_ - 1;

    const __half2* Gs = Gp + (size_t)g * N_ * 8;
    const int r0 = rowptr[n];
    const int r1 = rowptr[n + 1];

    const __half2 z = __float2half2_rn(0.f);
    __half2 acc0 = Gs[(size_t)n * 8 + cp];    // self term (contiguous 256B/wave)
    __half2 acc1 = z;

    int e = r0;
    const int emax = E_ - 1;
    while (__ballot(e < r1)) {
        bool p0 = e < r1;
        bool p1 = e + 1 < r1;
        int ec0 = min(e, emax);
        int ec1 = min(e + 1, emax);
        int s0 = cols[ec0];
        int s1 = cols[ec1];
        __half2 h0 = Gs[(size_t)s0 * 8 + cp];
        __half2 h1 = Gs[(size_t)s1 * 8 + cp];
        acc0 = __hadd2(acc0, p0 ? h0 : z);
        acc1 = __hadd2(acc1, p1 ? h1 : z);
        e += 2;
    }

    if (valid) {
        float2 s = __half22float2(__hadd2(acc0, acc1));
        float di = dinv[n];
        float2 bb = ((const float2*)bias)[g * 8 + cp];
        float o0 = fmaf(di, s.x, bb.x);
        float o1 = fmaf(di, s.y, bb.y);
        out[((size_t)g * N_ + n) * 8 + cp] = __floats2half2_rn(o0, o1);
    }
}

// ---------------- BN stats over group-major input ----------------
__global__ __launch_bounds__(256) void bn_stats_kernel(
    const __half2* __restrict__ X, float* __restrict__ gsum, float* __restrict__ gsq,
    int N_, int stride)
{
    __shared__ float ssum[4][128], ssq[4][128];
    const int wave = threadIdx.x >> 6;
    const int lane = threadIdx.x & 63;
    const size_t base = (size_t)(lane >> 3) * N_ * 8 + (lane & 7);
    float r0 = 0.f, r1 = 0.f, q0 = 0.f, q1 = 0.f;
    for (int n = blockIdx.x * 4 + wave; n < N_; n += stride) {
        float2 v = __half22float2(X[base + (size_t)n * 8]);
        r0 += v.x; r1 += v.y;
        q0 = fmaf(v.x, v.x, q0); q1 = fmaf(v.y, v.y, q1);
    }
    int c = lane * 2;   // channel = (lane>>3)*16 + (lane&7)*2 == 2*lane
    ssum[wave][c] = r0; ssum[wave][c + 1] = r1;
    ssq[wave][c]  = q0; ssq[wave][c + 1]  = q1;
    __syncthreads();
    if (threadIdx.x < 128) {
        int k = threadIdx.x;
        float s = (ssum[0][k] + ssum[1][k]) + (ssum[2][k] + ssum[3][k]);
        float q = (ssq[0][k] + ssq[1][k]) + (ssq[2][k] + ssq[3][k]);
        atomicAdd(&gsum[k], s);
        atomicAdd(&gsq[k], q);
    }
}

// ---------------- launch ----------------
extern "C" void kernel_launch(void* const* d_in, const int* in_sizes, int n_in,
                              void* d_out, int out_size, void* d_ws, size_t ws_size,
                              hipStream_t stream) {
    const float* x   = (const float*)d_in[0];
    const int* esrc  = (const int*)d_in[1];
    const int* edst  = (const int*)d_in[2];
    const float* W1  = (const float*)d_in[3];
    const float* b1  = (const float*)d_in[4];
    const float* g1  = (const float*)d_in[5];
    const float* bt1 = (const float*)d_in[6];
    const float* W2  = (const float*)d_in[7];
    const float* b2  = (const float*)d_in[8];
    const float* g2  = (const float*)d_in[9];
    const float* bt2 = (const float*)d_in[10];
    const float* Wr  = (const float*)d_in[11];
    const float* br  = (const float*)d_in[12];

    const int N_ = in_sizes[0] / H_DIM;     // 100000
    const int E_ = in_sizes[1];             // 1600000
    const int OUTC = out_size / N_;         // 40
    const float inv_n = 1.0f / (float)N_;

    char* p = (char*)d_ws;
    auto alloc = [&](size_t bytes) -> void* {
        void* r = (void*)p;
        p += (bytes + 255) & ~(size_t)255;
        return r;
    };
    __half* tmpA = (__half*)alloc((size_t)N_ * H_DIM * 2);
    __half* tmpB = (__half*)alloc((size_t)N_ * H_DIM * 2);
    int*   cols  = (int*)  alloc((size_t)E_ * 4);
    int*   rowptr= (int*)  alloc((size_t)(N_ + 1) * 4);
    size_t degcur_sz = ((size_t)2 * N_ * 4 + 255) & ~(size_t)255;
    int*   degcur= (int*)  alloc((size_t)2 * N_ * 4);
    float* bnbuf = (float*)alloc(4 * 128 * 4);
    int*   deg   = degcur;
    int*   cursor= degcur + N_;
    float* sum1 = bnbuf,       *sq1 = bnbuf + 128;
    float* sum2 = bnbuf + 256, *sq2 = bnbuf + 384;
    float* dinv  = (float*)alloc((size_t)N_ * 4);
    int*   bsum  = (int*)  alloc(4096);
    int*   boff  = (int*)  alloc(4096);

    hipMemsetAsync(degcur, 0, degcur_sz + 4 * 128 * 4, stream);  // deg+cursor+bn sums

    const int nb = (N_ + 255) / 256;
    const int eb = (E_ + 255) / 256;
    const int ntiles64 = (N_ + 63) / 64;
    const int agg_grid = ((N_ + 31) / 32) * 8;   // 4 waves x 8 nodes per block, x8 groups

    int shift = 0;                           // buckets (d>>shift) in 0..7
    while (((N_ - 1) >> shift) > 7) ++shift; // N=100000 -> shift=14, buckets 0..6

    const int BN_BLOCKS = 1024;
    const int BN_STRIDE = BN_BLOCKS * 4;

    degree_kernel<<<eb, 256, 0, stream>>>(edst, deg, E_);
    scan_block_kernel<<<nb, 256, 0, stream>>>(deg, dinv, rowptr, bsum, N_);
    scan_bsums_kernel<<<1, 512, 0, stream>>>(bsum, boff, nb);
    scan_add_kernel<<<nb, 256, 0, stream>>>(rowptr, boff, N_, E_);
    csr_fill_kernel<<<eb * 8, 256, 0, stream>>>(esrc, edst, rowptr, cursor, cols, E_, N_, shift);

    // layer 1: G1 = dinv .* (x @ W1)   (f32 row-major in, fp16 group-major out)
    gemm_mfma_kernel<false, float><<<ntiles64, 256, 0, stream>>>(
        x, W1, nullptr, nullptr, nullptr, nullptr, dinv,
        (_Float16*)tmpA, N_, inv_n);
    aggregate_kernel<<<agg_grid, 256, 0, stream>>>(
        (const __half2*)tmpA, rowptr, cols, dinv, b1, (__half2*)tmpB, N_, E_);
    bn_stats_kernel<<<BN_BLOCKS, 256, 0, stream>>>(
        (const __half2*)tmpB, sum1, sq1, N_, BN_STRIDE);

    // layer 2 (BN-finalize fused into GEMM prologue; group-major in/out)
    gemm_mfma_kernel<true, _Float16><<<ntiles64, 256, 0, stream>>>(
        (const _Float16*)tmpB, W2, sum1, sq1, g1, bt1, dinv,
        (_Float16*)tmpA, N_, inv_n);
    aggregate_kernel<<<agg_grid, 256, 0, stream>>>(
        (const __half2*)tmpA, rowptr, cols, dinv, b2, (__half2*)tmpB, N_, E_);
    bn_stats_kernel<<<BN_BLOCKS, 256, 0, stream>>>(
        (const __half2*)tmpB, sum2, sq2, N_, BN_STRIDE);

    // readout (MFMA, BN-finalize + bias fused, f32 row-major out)
    readout_mfma_kernel<<<ntiles64, 256, 0, stream>>>(
        (const _Float16*)tmpB, Wr, sum2, sq2, g2, bt2, br,
        (float*)d_out, N_, OUTC, inv_n);
}

// Round 10
// 570.814 us; speedup vs baseline: 1.4109x; 1.1000x over previous
//
#include <hip/hip_runtime.h>
#include <hip/hip_bf16.h>
#include <hip/hip_fp16.h>

#define H_DIM 128
#define BN_EPS 1e-5f

typedef _Float16 half8 __attribute__((ext_vector_type(8)));
typedef float floatx4 __attribute__((ext_vector_type(4)));

// Intermediates are GROUP-MAJOR: G[g][N+1][16] fp16, g=0..7; row N is all-zero
// (dummy target for padded CSR holes). aggregate launches blockIdx%8==g so each
// XCD's random gathers stay inside one ~3.2MB slice (L2-resident; R8/R9: FETCH
// 190->52MB). CSR is padded: deg_p=(deg+3)&~3, holes = N -> zero row, so the
// gather loop is predication-free (divergent exit via exec mask) with aligned
// int4 col loads.

// ---------------- prefill: cols=dummy(N), zero dummy rows of both buffers ----------------
__global__ void prefill_kernel(int* __restrict__ cols, int ncols4, int fillval,
                               __half2* __restrict__ dA, __half2* __restrict__ dB, int N1) {
    int i = blockIdx.x * 256 + threadIdx.x;
    int4 v = make_int4(fillval, fillval, fillval, fillval);
    for (int j = i; j < ncols4; j += gridDim.x * 256) ((int4*)cols)[j] = v;
    if (blockIdx.x == 0 && threadIdx.x < 128) {
        int t = threadIdx.x;
        int g = t >> 4, buf = (t >> 3) & 1, cp = t & 7;
        __half2* d = buf ? dB : dA;
        d[((size_t)g * N1 + (N1 - 1)) * 8 + cp] = __float2half2_rn(0.f);
    }
}

// ---------------- degree ----------------
__global__ void degree_kernel(const int* __restrict__ dst, int* __restrict__ deg, int E_) {
    int i = blockIdx.x * blockDim.x + threadIdx.x;
    if (i < E_) atomicAdd(&deg[dst[i]], 1);
}

// ---------------- exclusive scan over PADDED degrees; dinv from true deg ----------------
__global__ void scan_block_kernel(const int* __restrict__ deg, float* __restrict__ dinv,
                                  int* __restrict__ rowptr, int* __restrict__ bsum, int N_) {
    __shared__ int sh[256];
    int i = blockIdx.x * 256 + threadIdx.x;
    int v = (i < N_) ? deg[i] : 0;
    if (i < N_) dinv[i] = rsqrtf((float)v + 1.0f);
    int vp = (v + 3) & ~3;                        // padded degree
    sh[threadIdx.x] = vp;
    __syncthreads();
    for (int off = 1; off < 256; off <<= 1) {
        int t = (threadIdx.x >= off) ? sh[threadIdx.x - off] : 0;
        __syncthreads();
        sh[threadIdx.x] += t;
        __syncthreads();
    }
    if (i < N_) rowptr[i] = sh[threadIdx.x] - vp; // exclusive (4-aligned)
    if (threadIdx.x == 255) bsum[blockIdx.x] = sh[255];
}

__global__ void scan_bsums_kernel(const int* __restrict__ bsum, int* __restrict__ boff,
                                  int nb, int* __restrict__ rowptr, int N_) {
    __shared__ int sh[512];
    int v = (threadIdx.x < nb) ? bsum[threadIdx.x] : 0;
    sh[threadIdx.x] = v;
    __syncthreads();
    for (int off = 1; off < 512; off <<= 1) {
        int t = (threadIdx.x >= off) ? sh[threadIdx.x - off] : 0;
        __syncthreads();
        sh[threadIdx.x] += t;
        __syncthreads();
    }
    if (threadIdx.x < nb) boff[threadIdx.x] = sh[threadIdx.x] - v;  // exclusive
    if (threadIdx.x == nb - 1) rowptr[N_] = sh[threadIdx.x];        // E_padded total
}

__global__ void scan_add_kernel(int* __restrict__ rowptr, const int* __restrict__ boff, int N_) {
    int i = blockIdx.x * 256 + threadIdx.x;
    if (i < N_) rowptr[i] += boff[blockIdx.x];
}

// ---------------- CSR fill, XCD-binned by dst bucket ----------------
__global__ void csr_fill_kernel(const int* __restrict__ src, const int* __restrict__ dst,
                                const int* __restrict__ rowptr, int* __restrict__ cursor,
                                int* __restrict__ cols, int E_, int N_, int shift) {
    int b = blockIdx.x & 7;
    if (((N_ - 1) >> shift) < b) return;          // bucket never occurs
    int i = (blockIdx.x >> 3) * blockDim.x + threadIdx.x;
    if (i < E_) {
        int d = dst[i];
        if ((d >> shift) == b) {
            int p = rowptr[d] + atomicAdd(&cursor[d], 1);
            cols[p] = src[i];
        }
    }
}

// ---------------- MFMA fragment helpers ----------------
__device__ inline half8 a_frag_f32(const float* Xr, int k0) {
    float4 v0 = *(const float4*)(Xr + k0);
    float4 v1 = *(const float4*)(Xr + k0 + 4);
    half8 a;
    a[0] = (_Float16)v0.x; a[1] = (_Float16)v0.y; a[2] = (_Float16)v0.z; a[3] = (_Float16)v0.w;
    a[4] = (_Float16)v1.x; a[5] = (_Float16)v1.y; a[6] = (_Float16)v1.z; a[7] = (_Float16)v1.w;
    return a;
}
__device__ inline half8 a_frag_f16_bn(const _Float16* p8, int k0,
                                      const float* A, const float* B) {
    half8 r = *(const half8*)p8;
    half8 o;
#pragma unroll
    for (int u = 0; u < 8; ++u)
        o[u] = (_Float16)fmaxf(fmaf((float)r[u], A[k0 + u], B[k0 + u]), 0.f);
    return o;
}
__device__ inline const _Float16* gm_ptr(const _Float16* X, int N1, int row, int k0) {
    return X + ((size_t)(k0 >> 4) * N1 + row) * 16 + (k0 & 15);
}

// ---------------- MFMA GEMM: G'[g][n][16] = dinv .* (bnrelu(X) @ W[128,128]) ----------------
template<bool BN, typename InT>
__global__ __launch_bounds__(256) void gemm_mfma_kernel(
    const InT* __restrict__ X, const float* __restrict__ W,
    const float* __restrict__ gsum, const float* __restrict__ gsq,
    const float* __restrict__ gamma, const float* __restrict__ beta,
    const float* __restrict__ dinv,
    _Float16* __restrict__ Y, int N_, int N1, float inv_n)
{
    __shared__ _Float16 Wf[32 * 64 * 8];   // 32 KB: [nt*4+kb][lane][j]
    __shared__ float Abn[128], Bbn[128];

    const int tid = threadIdx.x;
    for (int idx = tid; idx < 128 * 32; idx += 256) {
        int k = idx >> 5;                   // 0..127
        int n0 = (idx & 31) * 4;
        float4 w = *(const float4*)(W + k * 128 + n0);
        int kb = k >> 5, q = (k >> 3) & 3, j = k & 7;
#pragma unroll
        for (int u = 0; u < 4; ++u) {
            int n = n0 + u;
            int lane = (n & 15) | (q << 4);
            Wf[((((n >> 4) * 4 + kb) * 64 + lane) << 3) + j] = (_Float16)((&w.x)[u]);
        }
    }
    if constexpr (BN) {
        if (tid < 128) {
            float mean = gsum[tid] * inv_n;
            float var = gsq[tid] * inv_n - mean * mean;
            float a = rsqrtf(var + BN_EPS) * gamma[tid];
            Abn[tid] = a;
            Bbn[tid] = beta[tid] - mean * a;
        }
    }
    __syncthreads();

    const int wv = tid >> 6, lane = tid & 63;
    const int m = lane & 15, q = lane >> 4;
    const int row0 = blockIdx.x * 64 + wv * 16;

    int arow = row0 + m;
    if (arow >= N_) arow = N_ - 1;

    half8 a[4];
#pragma unroll
    for (int kb = 0; kb < 4; ++kb) {
        int k0 = kb * 32 + q * 8;
        if constexpr (BN)
            a[kb] = a_frag_f16_bn(gm_ptr((const _Float16*)X, N1, arow, k0), k0, Abn, Bbn);
        else
            a[kb] = a_frag_f32((const float*)X + (size_t)arow * H_DIM, k0);
    }

    floatx4 acc[8];
#pragma unroll
    for (int nt = 0; nt < 8; ++nt) acc[nt] = (floatx4){0.f, 0.f, 0.f, 0.f};

#pragma unroll
    for (int nt = 0; nt < 8; ++nt) {
#pragma unroll
        for (int kb = 0; kb < 4; ++kb) {
            half8 b = *(const half8*)&Wf[(((nt * 4 + kb) * 64 + lane) << 3)];
            acc[nt] = __builtin_amdgcn_mfma_f32_16x16x32_f16(a[kb], b, acc[nt], 0, 0, 0);
        }
    }

#pragma unroll
    for (int r = 0; r < 4; ++r) {
        int row = row0 + q * 4 + r;
        if (row < N_) {
            float ds = dinv[row];
#pragma unroll
            for (int nt = 0; nt < 8; ++nt)
                Y[((size_t)nt * N1 + row) * 16 + m] = (_Float16)(ds * acc[nt][r]);
        }
    }
}

// ---------------- MFMA readout: Y[N,40] = bnrelu(X_gm) @ Wr[128,40] + br ----------------
__global__ __launch_bounds__(256) void readout_mfma_kernel(
    const _Float16* __restrict__ X, const float* __restrict__ W,   // [128, OUTC]
    const float* __restrict__ gsum, const float* __restrict__ gsq,
    const float* __restrict__ gamma, const float* __restrict__ beta,
    const float* __restrict__ br,
    float* __restrict__ Y, int N_, int N1, int OUTC, float inv_n)
{
    __shared__ _Float16 Wf[12 * 64 * 8];   // 12 KB: 3 n-tiles (48 cols padded)
    __shared__ float Abn[128], Bbn[128];

    const int tid = threadIdx.x;
    for (int idx = tid; idx < 128 * 64; idx += 256) {
        int k = idx >> 6, n = idx & 63;
        if (n < 48) {
            float w = (n < OUTC) ? W[k * OUTC + n] : 0.f;
            int kb = k >> 5, q = (k >> 3) & 3, j = k & 7;
            int lane = (n & 15) | (q << 4);
            Wf[((((n >> 4) * 4 + kb) * 64 + lane) << 3) + j] = (_Float16)w;
        }
    }
    if (tid < 128) {
        float mean = gsum[tid] * inv_n;
        float var = gsq[tid] * inv_n - mean * mean;
        float a = rsqrtf(var + BN_EPS) * gamma[tid];
        Abn[tid] = a;
        Bbn[tid] = beta[tid] - mean * a;
    }
    __syncthreads();

    const int wv = tid >> 6, lane = tid & 63;
    const int m = lane & 15, q = lane >> 4;
    const int row0 = blockIdx.x * 64 + wv * 16;

    int arow = row0 + m;
    if (arow >= N_) arow = N_ - 1;

    half8 a[4];
#pragma unroll
    for (int kb = 0; kb < 4; ++kb) {
        int k0 = kb * 32 + q * 8;
        a[kb] = a_frag_f16_bn(gm_ptr(X, N1, arow, k0), k0, Abn, Bbn);
    }

    floatx4 acc[3];
#pragma unroll
    for (int nt = 0; nt < 3; ++nt) acc[nt] = (floatx4){0.f, 0.f, 0.f, 0.f};

#pragma unroll
    for (int nt = 0; nt < 3; ++nt) {
#pragma unroll
        for (int kb = 0; kb < 4; ++kb) {
            half8 b = *(const half8*)&Wf[(((nt * 4 + kb) * 64 + lane) << 3)];
            acc[nt] = __builtin_amdgcn_mfma_f32_16x16x32_f16(a[kb], b, acc[nt], 0, 0, 0);
        }
    }

#pragma unroll
    for (int nt = 0; nt < 3; ++nt) {
        int col = nt * 16 + m;
        if (col < OUTC) {
            float bb = br[col];
#pragma unroll
            for (int r = 0; r < 4; ++r) {
                int row = row0 + q * 4 + r;
                if (row < N_)
                    Y[(size_t)row * OUTC + col] = acc[nt][r] + bb;
            }
        }
    }
}

// ---------------- aggregation, channel-split v4: padded CSR, predication-free ----------------
// blockIdx%8 = group g. Wave = 8 consecutive nodes: lane = ni*8+cp. Each 8-lane
// slice walks its node's padded edge list: 1 int4 col load + 4 gathers + 4
// pk-adds per 4 edges; divergent exit handled by exec mask (no cndmask/ballot).
__global__ __launch_bounds__(256) void aggregate_kernel(
    const __half2* __restrict__ Gp,           // [8][N1][8] half2
    const int* __restrict__ rowptr,           // padded, 4-aligned offsets
    const int* __restrict__ cols,             // padded, holes = N (zero row)
    const float* __restrict__ dinv, const float* __restrict__ bias,
    __half2* __restrict__ out, int N_, int N1)
{
    const int g = blockIdx.x & 7;
    const int wave = threadIdx.x >> 6;
    const int lane = threadIdx.x & 63;
    const int ni = lane >> 3;                 // node slot 0..7
    const int cp = lane & 7;                  // half2 channel index 0..7
    int n = ((blockIdx.x >> 3) * 4 + wave) * 8 + ni;
    const bool valid = n < N_;
    if (!valid) n = N_ - 1;

    const __half2* Gs = Gp + (size_t)g * N1 * 8;
    const int4* cols4 = (const int4*)cols;

    const __half2 z = __float2half2_rn(0.f);
    __half2 acc0 = Gs[(size_t)n * 8 + cp];    // self term (contiguous 256B/wave)
    __half2 acc1 = z, acc2 = z, acc3 = z;

    const int r1 = rowptr[n + 1];
    for (int e = rowptr[n]; e < r1; e += 4) {
        int4 c = cols4[e >> 2];
        __half2 h0 = Gs[(size_t)c.x * 8 + cp];
        __half2 h1 = Gs[(size_t)c.y * 8 + cp];
        __half2 h2 = Gs[(size_t)c.z * 8 + cp];
        __half2 h3 = Gs[(size_t)c.w * 8 + cp];
        acc0 = __hadd2(acc0, h0);
        acc1 = __hadd2(acc1, h1);
        acc2 = __hadd2(acc2, h2);
        acc3 = __hadd2(acc3, h3);
    }

    if (valid) {
        float2 s = __half22float2(__hadd2(__hadd2(acc0, acc1), __hadd2(acc2, acc3)));
        float di = dinv[n];
        float2 bb = ((const float2*)bias)[g * 8 + cp];
        float o0 = fmaf(di, s.x, bb.x);
        float o1 = fmaf(di, s.y, bb.y);
        out[((size_t)g * N1 + n) * 8 + cp] = __floats2half2_rn(o0, o1);
    }
}

// ---------------- BN stats over group-major input ----------------
__global__ __launch_bounds__(256) void bn_stats_kernel(
    const __half2* __restrict__ X, float* __restrict__ gsum, float* __restrict__ gsq,
    int N_, int N1, int stride)
{
    __shared__ float ssum[4][128], ssq[4][128];
    const int wave = threadIdx.x >> 6;
    const int lane = threadIdx.x & 63;
    const size_t base = (size_t)(lane >> 3) * N1 * 8 + (lane & 7);
    float r0 = 0.f, r1 = 0.f, q0 = 0.f, q1 = 0.f;
    for (int n = blockIdx.x * 4 + wave; n < N_; n += stride) {
        float2 v = __half22float2(X[base + (size_t)n * 8]);
        r0 += v.x; r1 += v.y;
        q0 = fmaf(v.x, v.x, q0); q1 = fmaf(v.y, v.y, q1);
    }
    int c = lane * 2;   // channel = (lane>>3)*16 + (lane&7)*2 == 2*lane
    ssum[wave][c] = r0; ssum[wave][c + 1] = r1;
    ssq[wave][c]  = q0; ssq[wave][c + 1]  = q1;
    __syncthreads();
    if (threadIdx.x < 128) {
        int k = threadIdx.x;
        float s = (ssum[0][k] + ssum[1][k]) + (ssum[2][k] + ssum[3][k]);
        float q = (ssq[0][k] + ssq[1][k]) + (ssq[2][k] + ssq[3][k]);
        atomicAdd(&gsum[k], s);
        atomicAdd(&gsq[k], q);
    }
}

// ---------------- launch ----------------
extern "C" void kernel_launch(void* const* d_in, const int* in_sizes, int n_in,
                              void* d_out, int out_size, void* d_ws, size_t ws_size,
                              hipStream_t stream) {
    const float* x   = (const float*)d_in[0];
    const int* esrc  = (const int*)d_in[1];
    const int* edst  = (const int*)d_in[2];
    const float* W1  = (const float*)d_in[3];
    const float* b1  = (const float*)d_in[4];
    const float* g1  = (const float*)d_in[5];
    const float* bt1 = (const float*)d_in[6];
    const float* W2  = (const float*)d_in[7];
    const float* b2  = (const float*)d_in[8];
    const float* g2  = (const float*)d_in[9];
    const float* bt2 = (const float*)d_in[10];
    const float* Wr  = (const float*)d_in[11];
    const float* br  = (const float*)d_in[12];

    const int N_ = in_sizes[0] / H_DIM;     // 100000
    const int E_ = in_sizes[1];             // 1600000
    const int OUTC = out_size / N_;         // 40
    const int N1 = N_ + 1;                  // +1 dummy zero row per group slice
    const float inv_n = 1.0f / (float)N_;

    char* p = (char*)d_ws;
    auto alloc = [&](size_t bytes) -> void* {
        void* r = (void*)p;
        p += (bytes + 255) & ~(size_t)255;
        return r;
    };
    const int cols_sz = E_ + 3 * N_ + 16;   // padded CSR capacity
    __half* tmpA = (__half*)alloc((size_t)N1 * H_DIM * 2);
    __half* tmpB = (__half*)alloc((size_t)N1 * H_DIM * 2);
    int*   cols  = (int*)  alloc((size_t)cols_sz * 4);
    int*   rowptr= (int*)  alloc((size_t)(N_ + 1) * 4);
    size_t degcur_sz = ((size_t)2 * N_ * 4 + 255) & ~(size_t)255;
    int*   degcur= (int*)  alloc((size_t)2 * N_ * 4);
    float* bnbuf = (float*)alloc(4 * 128 * 4);
    int*   deg   = degcur;
    int*   cursor= degcur + N_;
    float* sum1 = bnbuf,       *sq1 = bnbuf + 128;
    float* sum2 = bnbuf + 256, *sq2 = bnbuf + 384;
    float* dinv  = (float*)alloc((size_t)N_ * 4);
    int*   bsum  = (int*)  alloc(4096);
    int*   boff  = (int*)  alloc(4096);

    hipMemsetAsync(degcur, 0, degcur_sz + 4 * 128 * 4, stream);  // deg+cursor+bn sums

    const int nb = (N_ + 255) / 256;
    const int eb = (E_ + 255) / 256;
    const int ntiles64 = (N_ + 63) / 64;
    const int agg_grid = ((N_ + 31) / 32) * 8;   // 4 waves x 8 nodes per block, x8 groups

    int shift = 0;                           // buckets (d>>shift) in 0..7
    while (((N_ - 1) >> shift) > 7) ++shift; // N=100000 -> shift=14, buckets 0..6

    const int BN_BLOCKS = 1024;
    const int BN_STRIDE = BN_BLOCKS * 4;

    prefill_kernel<<<512, 256, 0, stream>>>(cols, cols_sz / 4, N_,
                                            (__half2*)tmpA, (__half2*)tmpB, N1);
    degree_kernel<<<eb, 256, 0, stream>>>(edst, deg, E_);
    scan_block_kernel<<<nb, 256, 0, stream>>>(deg, dinv, rowptr, bsum, N_);
    scan_bsums_kernel<<<1, 512, 0, stream>>>(bsum, boff, nb, rowptr, N_);
    scan_add_kernel<<<nb, 256, 0, stream>>>(rowptr, boff, N_);
    csr_fill_kernel<<<eb * 8, 256, 0, stream>>>(esrc, edst, rowptr, cursor, cols, E_, N_, shift);

    // layer 1: G1 = dinv .* (x @ W1)   (f32 row-major in, fp16 group-major out)
    gemm_mfma_kernel<false, float><<<ntiles64, 256, 0, stream>>>(
        x, W1, nullptr, nullptr, nullptr, nullptr, dinv,
        (_Float16*)tmpA, N_, N1, inv_n);
    aggregate_kernel<<<agg_grid, 256, 0, stream>>>(
        (const __half2*)tmpA, rowptr, cols, dinv, b1, (__half2*)tmpB, N_, N1);
    bn_stats_kernel<<<BN_BLOCKS, 256, 0, stream>>>(
        (const __half2*)tmpB, sum1, sq1, N_, N1, BN_STRIDE);

    // layer 2 (BN-finalize fused into GEMM prologue; group-major in/out)
    gemm_mfma_kernel<true, _Float16><<<ntiles64, 256, 0, stream>>>(
        (const _Float16*)tmpB, W2, sum1, sq1, g1, bt1, dinv,
        (_Float16*)tmpA, N_, N1, inv_n);
    aggregate_kernel<<<agg_grid, 256, 0, stream>>>(
        (const __half2*)tmpA, rowptr, cols, dinv, b2, (__half2*)tmpB, N_, N1);
    bn_stats_kernel<<<BN_BLOCKS, 256, 0, stream>>>(
        (const __half2*)tmpB, sum2, sq2, N_, N1, BN_STRIDE);

    // readout (MFMA, BN-finalize + bias fused, f32 row-major out)
    readout_mfma_kernel<<<ntiles64, 256, 0, stream>>>(
        (const _Float16*)tmpB, Wr, sum2, sq2, g2, bt2, br,
        (float*)d_out, N_, N1, OUTC, inv_n);
}

// Round 11
// 562.090 us; speedup vs baseline: 1.4328x; 1.0155x over previous
//
#include <hip/hip_runtime.h>
#include <hip/hip_bf16.h>
#include <hip/hip_fp16.h>

#define H_DIM 128
#define BN_EPS 1e-5f

typedef _Float16 half8 __attribute__((ext_vector_type(8)));
typedef float floatx4 __attribute__((ext_vector_type(4)));

// Intermediates are GROUP-MAJOR: G[g][N+1][16] fp16, g=0..7; row N is all-zero
// (dummy target for padded CSR holes). aggregate launches blockIdx%8==g so each
// XCD's random gathers stay inside one ~3.2MB slice (L2-resident; R8-R10: FETCH
// 190->57MB, residual = 8x cols stream). CSR padded: deg_p=(deg+3)&~3, holes=N.

// ---------------- prefill: cols=dummy(N), zero dummy rows of both buffers ----------------
__global__ void prefill_kernel(int* __restrict__ cols, int ncols4, int fillval,
                               __half2* __restrict__ dA, __half2* __restrict__ dB, int N1) {
    int i = blockIdx.x * 256 + threadIdx.x;
    int4 v = make_int4(fillval, fillval, fillval, fillval);
    for (int j = i; j < ncols4; j += gridDim.x * 256) ((int4*)cols)[j] = v;
    if (blockIdx.x == 0 && threadIdx.x < 128) {
        int t = threadIdx.x;
        int g = t >> 4, buf = (t >> 3) & 1, cp = t & 7;
        __half2* d = buf ? dB : dA;
        d[((size_t)g * N1 + (N1 - 1)) * 8 + cp] = __float2half2_rn(0.f);
    }
}

// ---------------- degree, XCD-binned by dst bucket (atomic lines stay XCD-private) ----------------
__global__ void degree_kernel(const int* __restrict__ dst, int* __restrict__ deg,
                              int E_, int N_, int shift) {
    int b = blockIdx.x & 7;
    if (((N_ - 1) >> shift) < b) return;
    int i = (blockIdx.x >> 3) * blockDim.x + threadIdx.x;
    if (i < E_) {
        int d = dst[i];
        if ((d >> shift) == b) atomicAdd(&deg[d], 1);
    }
}

// ---------------- exclusive scan over PADDED degrees; dinv from true deg ----------------
__global__ void scan_block_kernel(const int* __restrict__ deg, float* __restrict__ dinv,
                                  int* __restrict__ rowptr, int* __restrict__ bsum, int N_) {
    __shared__ int sh[256];
    int i = blockIdx.x * 256 + threadIdx.x;
    int v = (i < N_) ? deg[i] : 0;
    if (i < N_) dinv[i] = rsqrtf((float)v + 1.0f);
    int vp = (v + 3) & ~3;                        // padded degree
    sh[threadIdx.x] = vp;
    __syncthreads();
    for (int off = 1; off < 256; off <<= 1) {
        int t = (threadIdx.x >= off) ? sh[threadIdx.x - off] : 0;
        __syncthreads();
        sh[threadIdx.x] += t;
        __syncthreads();
    }
    if (i < N_) rowptr[i] = sh[threadIdx.x] - vp; // exclusive (4-aligned)
    if (threadIdx.x == 255) bsum[blockIdx.x] = sh[255];
}

__global__ void scan_bsums_kernel(const int* __restrict__ bsum, int* __restrict__ boff,
                                  int nb, int* __restrict__ rowptr, int N_) {
    __shared__ int sh[512];
    int v = (threadIdx.x < nb) ? bsum[threadIdx.x] : 0;
    sh[threadIdx.x] = v;
    __syncthreads();
    for (int off = 1; off < 512; off <<= 1) {
        int t = (threadIdx.x >= off) ? sh[threadIdx.x - off] : 0;
        __syncthreads();
        sh[threadIdx.x] += t;
        __syncthreads();
    }
    if (threadIdx.x < nb) boff[threadIdx.x] = sh[threadIdx.x] - v;  // exclusive
    if (threadIdx.x == nb - 1) rowptr[N_] = sh[threadIdx.x];        // E_padded total
}

__global__ void scan_add_kernel(int* __restrict__ rowptr, const int* __restrict__ boff, int N_) {
    int i = blockIdx.x * 256 + threadIdx.x;
    if (i < N_) rowptr[i] += boff[blockIdx.x];
}

// ---------------- CSR fill, XCD-binned by dst bucket ----------------
__global__ void csr_fill_kernel(const int* __restrict__ src, const int* __restrict__ dst,
                                const int* __restrict__ rowptr, int* __restrict__ cursor,
                                int* __restrict__ cols, int E_, int N_, int shift) {
    int b = blockIdx.x & 7;
    if (((N_ - 1) >> shift) < b) return;          // bucket never occurs
    int i = (blockIdx.x >> 3) * blockDim.x + threadIdx.x;
    if (i < E_) {
        int d = dst[i];
        if ((d >> shift) == b) {
            int p = rowptr[d] + atomicAdd(&cursor[d], 1);
            cols[p] = src[i];
        }
    }
}

// ---------------- MFMA fragment helpers ----------------
__device__ inline half8 a_frag_f32(const float* Xr, int k0) {
    float4 v0 = *(const float4*)(Xr + k0);
    float4 v1 = *(const float4*)(Xr + k0 + 4);
    half8 a;
    a[0] = (_Float16)v0.x; a[1] = (_Float16)v0.y; a[2] = (_Float16)v0.z; a[3] = (_Float16)v0.w;
    a[4] = (_Float16)v1.x; a[5] = (_Float16)v1.y; a[6] = (_Float16)v1.z; a[7] = (_Float16)v1.w;
    return a;
}
__device__ inline half8 a_frag_f16_bn(const _Float16* p8, int k0,
                                      const float* A, const float* B) {
    half8 r = *(const half8*)p8;
    half8 o;
#pragma unroll
    for (int u = 0; u < 8; ++u)
        o[u] = (_Float16)fmaxf(fmaf((float)r[u], A[k0 + u], B[k0 + u]), 0.f);
    return o;
}
__device__ inline const _Float16* gm_ptr(const _Float16* X, int N1, int row, int k0) {
    return X + ((size_t)(k0 >> 4) * N1 + row) * 16 + (k0 & 15);
}

// ---------------- MFMA GEMM: G'[g][n][16] = dinv .* (bnrelu(X) @ W[128,128]) ----------------
template<bool BN, typename InT>
__global__ __launch_bounds__(256) void gemm_mfma_kernel(
    const InT* __restrict__ X, const float* __restrict__ W,
    const float* __restrict__ gsum, const float* __restrict__ gsq,
    const float* __restrict__ gamma, const float* __restrict__ beta,
    const float* __restrict__ dinv,
    _Float16* __restrict__ Y, int N_, int N1, float inv_n)
{
    __shared__ _Float16 Wf[32 * 64 * 8];   // 32 KB: [nt*4+kb][lane][j]
    __shared__ float Abn[128], Bbn[128];

    const int tid = threadIdx.x;
    for (int idx = tid; idx < 128 * 32; idx += 256) {
        int k = idx >> 5;                   // 0..127
        int n0 = (idx & 31) * 4;
        float4 w = *(const float4*)(W + k * 128 + n0);
        int kb = k >> 5, q = (k >> 3) & 3, j = k & 7;
#pragma unroll
        for (int u = 0; u < 4; ++u) {
            int n = n0 + u;
            int lane = (n & 15) | (q << 4);
            Wf[((((n >> 4) * 4 + kb) * 64 + lane) << 3) + j] = (_Float16)((&w.x)[u]);
        }
    }
    if constexpr (BN) {
        if (tid < 128) {
            float mean = gsum[tid] * inv_n;
            float var = gsq[tid] * inv_n - mean * mean;
            float a = rsqrtf(var + BN_EPS) * gamma[tid];
            Abn[tid] = a;
            Bbn[tid] = beta[tid] - mean * a;
        }
    }
    __syncthreads();

    const int wv = tid >> 6, lane = tid & 63;
    const int m = lane & 15, q = lane >> 4;
    const int row0 = blockIdx.x * 64 + wv * 16;

    int arow = row0 + m;
    if (arow >= N_) arow = N_ - 1;

    half8 a[4];
#pragma unroll
    for (int kb = 0; kb < 4; ++kb) {
        int k0 = kb * 32 + q * 8;
        if constexpr (BN)
            a[kb] = a_frag_f16_bn(gm_ptr((const _Float16*)X, N1, arow, k0), k0, Abn, Bbn);
        else
            a[kb] = a_frag_f32((const float*)X + (size_t)arow * H_DIM, k0);
    }

    floatx4 acc[8];
#pragma unroll
    for (int nt = 0; nt < 8; ++nt) acc[nt] = (floatx4){0.f, 0.f, 0.f, 0.f};

#pragma unroll
    for (int nt = 0; nt < 8; ++nt) {
#pragma unroll
        for (int kb = 0; kb < 4; ++kb) {
            half8 b = *(const half8*)&Wf[(((nt * 4 + kb) * 64 + lane) << 3)];
            acc[nt] = __builtin_amdgcn_mfma_f32_16x16x32_f16(a[kb], b, acc[nt], 0, 0, 0);
        }
    }

#pragma unroll
    for (int r = 0; r < 4; ++r) {
        int row = row0 + q * 4 + r;
        if (row < N_) {
            float ds = dinv[row];
#pragma unroll
            for (int nt = 0; nt < 8; ++nt)
                Y[((size_t)nt * N1 + row) * 16 + m] = (_Float16)(ds * acc[nt][r]);
        }
    }
}

// ---------------- MFMA readout: Y[N,40] = bnrelu(X_gm) @ Wr[128,40] + br ----------------
__global__ __launch_bounds__(256) void readout_mfma_kernel(
    const _Float16* __restrict__ X, const float* __restrict__ W,   // [128, OUTC]
    const float* __restrict__ gsum, const float* __restrict__ gsq,
    const float* __restrict__ gamma, const float* __restrict__ beta,
    const float* __restrict__ br,
    float* __restrict__ Y, int N_, int N1, int OUTC, float inv_n)
{
    __shared__ _Float16 Wf[12 * 64 * 8];   // 12 KB: 3 n-tiles (48 cols padded)
    __shared__ float Abn[128], Bbn[128];

    const int tid = threadIdx.x;
    for (int idx = tid; idx < 128 * 64; idx += 256) {
        int k = idx >> 6, n = idx & 63;
        if (n < 48) {
            float w = (n < OUTC) ? W[k * OUTC + n] : 0.f;
            int kb = k >> 5, q = (k >> 3) & 3, j = k & 7;
            int lane = (n & 15) | (q << 4);
            Wf[((((n >> 4) * 4 + kb) * 64 + lane) << 3) + j] = (_Float16)w;
        }
    }
    if (tid < 128) {
        float mean = gsum[tid] * inv_n;
        float var = gsq[tid] * inv_n - mean * mean;
        float a = rsqrtf(var + BN_EPS) * gamma[tid];
        Abn[tid] = a;
        Bbn[tid] = beta[tid] - mean * a;
    }
    __syncthreads();

    const int wv = tid >> 6, lane = tid & 63;
    const int m = lane & 15, q = lane >> 4;
    const int row0 = blockIdx.x * 64 + wv * 16;

    int arow = row0 + m;
    if (arow >= N_) arow = N_ - 1;

    half8 a[4];
#pragma unroll
    for (int kb = 0; kb < 4; ++kb) {
        int k0 = kb * 32 + q * 8;
        a[kb] = a_frag_f16_bn(gm_ptr(X, N1, arow, k0), k0, Abn, Bbn);
    }

    floatx4 acc[3];
#pragma unroll
    for (int nt = 0; nt < 3; ++nt) acc[nt] = (floatx4){0.f, 0.f, 0.f, 0.f};

#pragma unroll
    for (int nt = 0; nt < 3; ++nt) {
#pragma unroll
        for (int kb = 0; kb < 4; ++kb) {
            half8 b = *(const half8*)&Wf[(((nt * 4 + kb) * 64 + lane) << 3)];
            acc[nt] = __builtin_amdgcn_mfma_f32_16x16x32_f16(a[kb], b, acc[nt], 0, 0, 0);
        }
    }

#pragma unroll
    for (int nt = 0; nt < 3; ++nt) {
        int col = nt * 16 + m;
        if (col < OUTC) {
            float bb = br[col];
#pragma unroll
            for (int r = 0; r < 4; ++r) {
                int row = row0 + q * 4 + r;
                if (row < N_)
                    Y[(size_t)row * OUTC + col] = acc[nt][r] + bb;
            }
        }
    }
}

// ---------------- aggregation, channel-split v5: padded CSR, 8 gathers/iter ----------------
// blockIdx%8 = group g. Wave = 8 consecutive nodes: lane = ni*8+cp. Each 8-lane
// slice walks its node's padded edge list: 2 int4 col loads + 8 gathers + 8
// pk-adds per 8 edges; divergent exit via exec mask; tail handles 4.
__global__ __launch_bounds__(256) void aggregate_kernel(
    const __half2* __restrict__ Gp,           // [8][N1][8] half2
    const int* __restrict__ rowptr,           // padded, 4-aligned offsets
    const int* __restrict__ cols,             // padded, holes = N (zero row)
    const float* __restrict__ dinv, const float* __restrict__ bias,
    __half2* __restrict__ out, int N_, int N1)
{
    const int g = blockIdx.x & 7;
    const int wave = threadIdx.x >> 6;
    const int lane = threadIdx.x & 63;
    const int ni = lane >> 3;                 // node slot 0..7
    const int cp = lane & 7;                  // half2 channel index 0..7
    int n = ((blockIdx.x >> 3) * 4 + wave) * 8 + ni;
    const bool valid = n < N_;
    if (!valid) n = N_ - 1;

    const __half2* Gs = Gp + (size_t)g * N1 * 8;
    const int4* cols4 = (const int4*)cols;

    const __half2 z = __float2half2_rn(0.f);
    __half2 acc0 = Gs[(size_t)n * 8 + cp];    // self term (contiguous 256B/wave)
    __half2 acc1 = z, acc2 = z, acc3 = z;

    int e = rowptr[n];
    const int r1 = rowptr[n + 1];
    for (; e + 8 <= r1; e += 8) {
        int4 c0 = cols4[e >> 2];
        int4 c1 = cols4[(e >> 2) + 1];
        __half2 h0 = Gs[(size_t)c0.x * 8 + cp];
        __half2 h1 = Gs[(size_t)c0.y * 8 + cp];
        __half2 h2 = Gs[(size_t)c0.z * 8 + cp];
        __half2 h3 = Gs[(size_t)c0.w * 8 + cp];
        __half2 h4 = Gs[(size_t)c1.x * 8 + cp];
        __half2 h5 = Gs[(size_t)c1.y * 8 + cp];
        __half2 h6 = Gs[(size_t)c1.z * 8 + cp];
        __half2 h7 = Gs[(size_t)c1.w * 8 + cp];
        acc0 = __hadd2(acc0, h0);
        acc1 = __hadd2(acc1, h1);
        acc2 = __hadd2(acc2, h2);
        acc3 = __hadd2(acc3, h3);
        acc0 = __hadd2(acc0, h4);
        acc1 = __hadd2(acc1, h5);
        acc2 = __hadd2(acc2, h6);
        acc3 = __hadd2(acc3, h7);
    }
    if (e < r1) {                             // one padded int4 remains
        int4 c = cols4[e >> 2];
        __half2 h0 = Gs[(size_t)c.x * 8 + cp];
        __half2 h1 = Gs[(size_t)c.y * 8 + cp];
        __half2 h2 = Gs[(size_t)c.z * 8 + cp];
        __half2 h3 = Gs[(size_t)c.w * 8 + cp];
        acc0 = __hadd2(acc0, h0);
        acc1 = __hadd2(acc1, h1);
        acc2 = __hadd2(acc2, h2);
        acc3 = __hadd2(acc3, h3);
    }

    if (valid) {
        float2 s = __half22float2(__hadd2(__hadd2(acc0, acc1), __hadd2(acc2, acc3)));
        float di = dinv[n];
        float2 bb = ((const float2*)bias)[g * 8 + cp];
        float o0 = fmaf(di, s.x, bb.x);
        float o1 = fmaf(di, s.y, bb.y);
        out[((size_t)g * N1 + n) * 8 + cp] = __floats2half2_rn(o0, o1);
    }
}

// ---------------- BN stats over group-major input ----------------
__global__ __launch_bounds__(256) void bn_stats_kernel(
    const __half2* __restrict__ X, float* __restrict__ gsum, float* __restrict__ gsq,
    int N_, int N1, int stride)
{
    __shared__ float ssum[4][128], ssq[4][128];
    const int wave = threadIdx.x >> 6;
    const int lane = threadIdx.x & 63;
    const size_t base = (size_t)(lane >> 3) * N1 * 8 + (lane & 7);
    float r0 = 0.f, r1 = 0.f, q0 = 0.f, q1 = 0.f;
    for (int n = blockIdx.x * 4 + wave; n < N_; n += stride) {
        float2 v = __half22float2(X[base + (size_t)n * 8]);
        r0 += v.x; r1 += v.y;
        q0 = fmaf(v.x, v.x, q0); q1 = fmaf(v.y, v.y, q1);
    }
    int c = lane * 2;   // channel = (lane>>3)*16 + (lane&7)*2 == 2*lane
    ssum[wave][c] = r0; ssum[wave][c + 1] = r1;
    ssq[wave][c]  = q0; ssq[wave][c + 1]  = q1;
    __syncthreads();
    if (threadIdx.x < 128) {
        int k = threadIdx.x;
        float s = (ssum[0][k] + ssum[1][k]) + (ssum[2][k] + ssum[3][k]);
        float q = (ssq[0][k] + ssq[1][k]) + (ssq[2][k] + ssq[3][k]);
        atomicAdd(&gsum[k], s);
        atomicAdd(&gsq[k], q);
    }
}

// ---------------- launch ----------------
extern "C" void kernel_launch(void* const* d_in, const int* in_sizes, int n_in,
                              void* d_out, int out_size, void* d_ws, size_t ws_size,
                              hipStream_t stream) {
    const float* x   = (const float*)d_in[0];
    const int* esrc  = (const int*)d_in[1];
    const int* edst  = (const int*)d_in[2];
    const float* W1  = (const float*)d_in[3];
    const float* b1  = (const float*)d_in[4];
    const float* g1  = (const float*)d_in[5];
    const float* bt1 = (const float*)d_in[6];
    const float* W2  = (const float*)d_in[7];
    const float* b2  = (const float*)d_in[8];
    const float* g2  = (const float*)d_in[9];
    const float* bt2 = (const float*)d_in[10];
    const float* Wr  = (const float*)d_in[11];
    const float* br  = (const float*)d_in[12];

    const int N_ = in_sizes[0] / H_DIM;     // 100000
    const int E_ = in_sizes[1];             // 1600000
    const int OUTC = out_size / N_;         // 40
    const int N1 = N_ + 1;                  // +1 dummy zero row per group slice
    const float inv_n = 1.0f / (float)N_;

    char* p = (char*)d_ws;
    auto alloc = [&](size_t bytes) -> void* {
        void* r = (void*)p;
        p += (bytes + 255) & ~(size_t)255;
        return r;
    };
    const int cols_sz = E_ + 3 * N_ + 16;   // padded CSR capacity
    __half* tmpA = (__half*)alloc((size_t)N1 * H_DIM * 2);
    __half* tmpB = (__half*)alloc((size_t)N1 * H_DIM * 2);
    int*   cols  = (int*)  alloc((size_t)cols_sz * 4);
    int*   rowptr= (int*)  alloc((size_t)(N_ + 1) * 4);
    size_t degcur_sz = ((size_t)2 * N_ * 4 + 255) & ~(size_t)255;
    int*   degcur= (int*)  alloc((size_t)2 * N_ * 4);
    float* bnbuf = (float*)alloc(4 * 128 * 4);
    int*   deg   = degcur;
    int*   cursor= degcur + N_;
    float* sum1 = bnbuf,       *sq1 = bnbuf + 128;
    float* sum2 = bnbuf + 256, *sq2 = bnbuf + 384;
    float* dinv  = (float*)alloc((size_t)N_ * 4);
    int*   bsum  = (int*)  alloc(4096);
    int*   boff  = (int*)  alloc(4096);

    hipMemsetAsync(degcur, 0, degcur_sz + 4 * 128 * 4, stream);  // deg+cursor+bn sums

    const int nb = (N_ + 255) / 256;
    const int eb = (E_ + 255) / 256;
    const int ntiles64 = (N_ + 63) / 64;
    const int agg_grid = ((N_ + 31) / 32) * 8;   // 4 waves x 8 nodes per block, x8 groups

    int shift = 0;                           // buckets (d>>shift) in 0..7
    while (((N_ - 1) >> shift) > 7) ++shift; // N=100000 -> shift=14, buckets 0..6

    const int BN_BLOCKS = 1024;
    const int BN_STRIDE = BN_BLOCKS * 4;

    prefill_kernel<<<512, 256, 0, stream>>>(cols, cols_sz / 4, N_,
                                            (__half2*)tmpA, (__half2*)tmpB, N1);
    degree_kernel<<<eb * 8, 256, 0, stream>>>(edst, deg, E_, N_, shift);
    scan_block_kernel<<<nb, 256, 0, stream>>>(deg, dinv, rowptr, bsum, N_);
    scan_bsums_kernel<<<1, 512, 0, stream>>>(bsum, boff, nb, rowptr, N_);
    scan_add_kernel<<<nb, 256, 0, stream>>>(rowptr, boff, N_);
    csr_fill_kernel<<<eb * 8, 256, 0, stream>>>(esrc, edst, rowptr, cursor, cols, E_, N_, shift);

    // layer 1: G1 = dinv .* (x @ W1)   (f32 row-major in, fp16 group-major out)
    gemm_mfma_kernel<false, float><<<ntiles64, 256, 0, stream>>>(
        x, W1, nullptr, nullptr, nullptr, nullptr, dinv,
        (_Float16*)tmpA, N_, N1, inv_n);
    aggregate_kernel<<<agg_grid, 256, 0, stream>>>(
        (const __half2*)tmpA, rowptr, cols, dinv, b1, (__half2*)tmpB, N_, N1);
    bn_stats_kernel<<<BN_BLOCKS, 256, 0, stream>>>(
        (const __half2*)tmpB, sum1, sq1, N_, N1, BN_STRIDE);

    // layer 2 (BN-finalize fused into GEMM prologue; group-major in/out)
    gemm_mfma_kernel<true, _Float16><<<ntiles64, 256, 0, stream>>>(
        (const _Float16*)tmpB, W2, sum1, sq1, g1, bt1, dinv,
        (_Float16*)tmpA, N_, N1, inv_n);
    aggregate_kernel<<<agg_grid, 256, 0, stream>>>(
        (const __half2*)tmpA, rowptr, cols, dinv, b2, (__half2*)tmpB, N_, N1);
    bn_stats_kernel<<<BN_BLOCKS, 256, 0, stream>>>(
        (const __half2*)tmpB, sum2, sq2, N_, N1, BN_STRIDE);

    // readout (MFMA, BN-finalize + bias fused, f32 row-major out)
    readout_mfma_kernel<<<ntiles64, 256, 0, stream>>>(
        (const _Float16*)tmpB, Wr, sum2, sq2, g2, bt2, br,
        (float*)d_out, N_, N1, OUTC, inv_n);
}